// Round 1
// baseline (779.966 us; speedup 1.0000x reference)
//
#include <hip/hip_runtime.h>
#include <math.h>

#define N_SAMP   64000
#define BATCH    32
#define CHUNK    256
#define NCHUNK   250      // 64000 / 256
#define NH       64

// ---------------------------------------------------------------------------
// Kernel 1: per-chunk sums of f0 in double. grid = BATCH*NCHUNK blocks x 256.
// Chunk c of row r covers samples [c*256, (c+1)*256); since rows are
// contiguous, flat chunk bx covers f0[bx*256 .. bx*256+255].
// ---------------------------------------------------------------------------
__global__ __launch_bounds__(256) void chunk_sum_kernel(
        const float* __restrict__ f0, double* __restrict__ csum) {
    int bx = blockIdx.x;
    int t  = threadIdx.x;
    double v = (double)f0[(long)bx * CHUNK + t];
    for (int off = 32; off > 0; off >>= 1) v += __shfl_down(v, off, 64);
    __shared__ double ws[4];
    int lane = t & 63, w = t >> 6;
    if (lane == 0) ws[w] = v;
    __syncthreads();
    if (t == 0) csum[bx] = ws[0] + ws[1] + ws[2] + ws[3];
}

// ---------------------------------------------------------------------------
// Kernel 2: per-row EXCLUSIVE scan of the NCHUNK chunk sums (in place).
// grid = BATCH blocks x 256 threads.
// ---------------------------------------------------------------------------
__global__ __launch_bounds__(256) void chunk_scan_kernel(double* __restrict__ csum) {
    int r = blockIdx.x;
    int t = threadIdx.x;
    double orig = (t < NCHUNK) ? csum[(long)r * NCHUNK + t] : 0.0;
    double v = orig;
    int lane = t & 63, w = t >> 6;
    for (int off = 1; off < 64; off <<= 1) {
        double n = __shfl_up(v, off, 64);
        if (lane >= off) v += n;
    }
    __shared__ double wsum[4];
    if (lane == 63) wsum[w] = v;
    __syncthreads();
    double add = 0.0;
    for (int i = 0; i < w; ++i) add += wsum[i];
    v += add;
    if (t < NCHUNK) csum[(long)r * NCHUNK + t] = v - orig;   // exclusive prefix
}

// ---------------------------------------------------------------------------
// Kernel 3: main oscillator. One block = 256 consecutive samples of one row.
// Phase A: block-wide inclusive scan of f0 (double) + chunk offset -> nu
//          (revolutions, reduced mod 1 in double).
// Phase B: 4 chunks of 16 harmonics; amplitudes staged via coalesced global
//          loads into LDS (stride 17 words: conflict-free reads), each thread
//          accumulates S1 = sum(w_h), S2 = sum(w_h * sin) for its sample.
// out = scale(amp0) * S2 / (S1 + 1e-5)
// ---------------------------------------------------------------------------
__device__ __forceinline__ float scale_fn(float x) {
    // 2 * sigmoid(x)^ln(10) + 1e-7  =  2 * (1+e^-x)^(-ln10) + 1e-7
    float e = exp2f(-1.4426950408889634f * x);       // e^{-x}
    float l = log2f(1.0f + e);
    return 2.0f * exp2f(-2.302585092994046f * l) + 1e-7f;
}

__global__ __launch_bounds__(256) void osc_kernel(
        const float* __restrict__ f0,
        const float* __restrict__ ha,
        const float* __restrict__ phase,
        const double* __restrict__ csum,
        float* __restrict__ out) {
    int bx = blockIdx.x;
    int r  = bx / NCHUNK;
    int t  = threadIdx.x;
    int lane = t & 63, w = t >> 6;

    long sbase = (long)bx * CHUNK;              // flat sample index base
    const float* hablk = ha + sbase * 65;       // this block's amplitude rows

    float f0v  = f0[sbase + t];
    float traw = hablk[t * 65];                 // raw total-amplitude (idx 0)

    // ---- Phase A: inclusive scan of f0 in double -> nu (revolutions) ----
    double v = (double)f0v;
    for (int off = 1; off < 64; off <<= 1) {
        double n = __shfl_up(v, off, 64);
        if (lane >= off) v += n;
    }
    __shared__ double wsum[4];
    if (lane == 63) wsum[w] = v;
    __syncthreads();
    double add = 0.0;
    for (int i = 0; i < w; ++i) add += wsum[i];
    v += add + csum[bx];
    double x = v * (1.0 / 44100.0) + (double)phase[r] * 0.15915494309189535;
    x -= floor(x);
    float nu = (float)x;                         // [0,1) revolutions

    // ---- Phase B: harmonic accumulation ----
    __shared__ float amp[CHUNK * 17];            // 16 harmonics + 1 pad per sample
    float S1 = 0.0f, S2 = 0.0f;
    const float half_sr = 22050.0f;
    int k  = t & 15;
    int sg = t >> 4;

    for (int hc = 0; hc < 4; ++hc) {
        __syncthreads();                          // previous chunk fully consumed
        // stage: 256 samples x 16 harmonics, coalesced in 64B segments
        int hb = 1 + hc * 16 + k;
        #pragma unroll
        for (int j = 0; j < 16; ++j) {
            int s = j * 16 + sg;
            amp[s * 17 + k] = hablk[(long)s * 65 + hb];
        }
        __syncthreads();
        #pragma unroll
        for (int k2 = 0; k2 < 16; ++k2) {
            float hf = (float)(hc * 16 + k2 + 1);
            float a  = amp[t * 17 + k2];
            float wv = scale_fn(a);
            wv = (f0v * hf < half_sr) ? wv : 0.0f;
            float t1 = nu * hf;
            float fr = t1 - floorf(t1);
            float sv = __sinf(6.283185307179586f * fr);
            S1 += wv;
            S2 = fmaf(wv, sv, S2);
        }
    }

    float total = scale_fn(traw);
    out[sbase + t] = total * S2 / (S1 + 1e-5f);
}

// ---------------------------------------------------------------------------
extern "C" void kernel_launch(void* const* d_in, const int* in_sizes, int n_in,
                              void* d_out, int out_size, void* d_ws, size_t ws_size,
                              hipStream_t stream) {
    const float* f0    = (const float*)d_in[0];   // (32, 64000)
    const float* ha    = (const float*)d_in[1];   // (32, 64000, 65)
    const float* phase = (const float*)d_in[2];   // (32,)
    float* out = (float*)d_out;                   // (32, 64000)
    double* csum = (double*)d_ws;                 // BATCH*NCHUNK doubles = 64 KB

    chunk_sum_kernel<<<BATCH * NCHUNK, 256, 0, stream>>>(f0, csum);
    chunk_scan_kernel<<<BATCH, 256, 0, stream>>>(csum);
    osc_kernel<<<BATCH * NCHUNK, 256, 0, stream>>>(f0, ha, phase, csum, out);
}

// Round 2
// 719.728 us; speedup vs baseline: 1.0837x; 1.0837x over previous
//
#include <hip/hip_runtime.h>
#include <math.h>

#define N_SAMP   64000
#define BATCH    32
#define CHUNK    128
#define NCHUNK   500      // 64000 / 128
#define NH       64

// ---------------------------------------------------------------------------
// Kernel 1: per-chunk sums of f0 in double. grid = BATCH*NCHUNK blocks x 128.
// Flat chunk bx covers f0[bx*128 .. bx*128+127].
// ---------------------------------------------------------------------------
__global__ __launch_bounds__(128) void chunk_sum_kernel(
        const float* __restrict__ f0, double* __restrict__ csum) {
    int bx = blockIdx.x;
    int t  = threadIdx.x;
    double v = (double)f0[(long)bx * CHUNK + t];
    for (int off = 32; off > 0; off >>= 1) v += __shfl_down(v, off, 64);
    __shared__ double ws[2];
    if ((t & 63) == 0) ws[t >> 6] = v;
    __syncthreads();
    if (t == 0) csum[bx] = ws[0] + ws[1];
}

// ---------------------------------------------------------------------------
// Kernel 2: per-row EXCLUSIVE scan of the NCHUNK chunk sums (in place).
// grid = BATCH blocks x 512 threads (500 active).
// ---------------------------------------------------------------------------
__global__ __launch_bounds__(512) void chunk_scan_kernel(double* __restrict__ csum) {
    int r = blockIdx.x;
    int t = threadIdx.x;
    int lane = t & 63, w = t >> 6;
    double orig = (t < NCHUNK) ? csum[(long)r * NCHUNK + t] : 0.0;
    double v = orig;
    for (int off = 1; off < 64; off <<= 1) {
        double n = __shfl_up(v, off, 64);
        if (lane >= off) v += n;
    }
    __shared__ double wsum[8];
    if (lane == 63) wsum[w] = v;
    __syncthreads();
    double add = 0.0;
    for (int i = 0; i < w; ++i) add += wsum[i];
    v += add;
    if (t < NCHUNK) csum[(long)r * NCHUNK + t] = v - orig;   // exclusive prefix
}

// ---------------------------------------------------------------------------
// Kernel 3: main oscillator. One block = 128 consecutive samples of one row.
// Stage the FULL 128x65-float amplitude slab into LDS in ONE contiguous
// coalesced float4 pass (each 260B row fetched exactly once -> no over-fetch),
// then compute all 64 harmonics from LDS.
// LDS read amp[t*65+1+h]: lane stride 65 (odd) -> 2 lanes/bank -> conflict-free.
// ---------------------------------------------------------------------------
__device__ __forceinline__ float scale_fn(float x) {
    // 2 * sigmoid(x)^ln(10) + 1e-7  =  2 * (1+e^-x)^(-ln10) + 1e-7
    float e = exp2f(-1.4426950408889634f * x);       // e^{-x}
    float l = log2f(1.0f + e);
    return 2.0f * exp2f(-2.302585092994046f * l) + 1e-7f;
}

__global__ __launch_bounds__(128) void osc_kernel(
        const float* __restrict__ f0,
        const float* __restrict__ ha,
        const float* __restrict__ phase,
        const double* __restrict__ csum,
        float* __restrict__ out) {
    int bx = blockIdx.x;
    int r  = bx / NCHUNK;
    int t  = threadIdx.x;
    int lane = t & 63, w = t >> 6;

    long sbase = (long)bx * CHUNK;              // flat sample index base
    const float* hablk = ha + sbase * 65;       // this block's amplitude slab

    // ---- stage full slab: 128*65 = 8320 floats = 2080 float4, contiguous ----
    __shared__ float amp[CHUNK * 65];           // 33,280 B
    {
        const float4* src = (const float4*)hablk;
        float4* dst = (float4*)amp;
        #pragma unroll
        for (int i = 0; i < 16; ++i)
            dst[i * 128 + t] = src[i * 128 + t];
        if (t < 2080 - 16 * 128)                // tail: 32 float4
            dst[16 * 128 + t] = src[16 * 128 + t];
    }

    float f0v = f0[sbase + t];

    // ---- inclusive scan of f0 in double -> nu (revolutions) ----
    double v = (double)f0v;
    for (int off = 1; off < 64; off <<= 1) {
        double n = __shfl_up(v, off, 64);
        if (lane >= off) v += n;
    }
    __shared__ double wsum[2];
    if (lane == 63) wsum[w] = v;
    __syncthreads();                            // covers staging + wsum
    if (w == 1) v += wsum[0];
    v += csum[bx];
    double x = v * (1.0 / 44100.0) + (double)phase[r] * 0.15915494309189535;
    x -= floor(x);
    float nu = (float)x;                        // [0,1) revolutions

    // ---- harmonic accumulation, single pass over LDS row ----
    float traw = amp[t * 65];                   // raw total-amplitude (idx 0)
    float S1 = 0.0f, S2 = 0.0f;
    const float half_sr = 22050.0f;
    #pragma unroll 16
    for (int h = 0; h < 64; ++h) {
        float hf = (float)(h + 1);
        float a  = amp[t * 65 + 1 + h];
        float wv = scale_fn(a);
        wv = (f0v * hf < half_sr) ? wv : 0.0f;
        float t1 = nu * hf;
        float fr = t1 - floorf(t1);
        float sv = __sinf(6.283185307179586f * fr);
        S1 += wv;
        S2 = fmaf(wv, sv, S2);
    }

    out[sbase + t] = scale_fn(traw) * S2 / (S1 + 1e-5f);
}

// ---------------------------------------------------------------------------
extern "C" void kernel_launch(void* const* d_in, const int* in_sizes, int n_in,
                              void* d_out, int out_size, void* d_ws, size_t ws_size,
                              hipStream_t stream) {
    const float* f0    = (const float*)d_in[0];   // (32, 64000)
    const float* ha    = (const float*)d_in[1];   // (32, 64000, 65)
    const float* phase = (const float*)d_in[2];   // (32,)
    float* out = (float*)d_out;                   // (32, 64000)
    double* csum = (double*)d_ws;                 // BATCH*NCHUNK doubles = 128 KB

    chunk_sum_kernel<<<BATCH * NCHUNK, CHUNK, 0, stream>>>(f0, csum);
    chunk_scan_kernel<<<BATCH, 512, 0, stream>>>(csum);
    osc_kernel<<<BATCH * NCHUNK, CHUNK, 0, stream>>>(f0, ha, phase, csum, out);
}

// Round 3
// 697.380 us; speedup vs baseline: 1.1184x; 1.0320x over previous
//
#include <hip/hip_runtime.h>
#include <math.h>

#define BATCH    32
#define CHUNK    128
#define NCHUNK   500      // 64000 / 128
#define TAB_N    1152     // 9*128 floats; entries 0..1023 cover x in [-8,8), rest pad

// ---------------------------------------------------------------------------
// exact scale function: 2 * sigmoid(x)^ln(10) + 1e-7 = 2*(1+e^-x)^(-ln10)+1e-7
// ---------------------------------------------------------------------------
__device__ __forceinline__ float scale_fn(float x) {
    float e = exp2f(-1.4426950408889634f * x);       // e^{-x}
    float l = log2f(1.0f + e);
    return 2.0f * exp2f(-2.302585092994046f * l) + 1e-7f;
}

// ---------------------------------------------------------------------------
// Kernel 0: build the scale_fn lookup table in global ws (rebuilt every call —
// harness re-poisons ws). Entry i = scale_fn(-8 + i/64).
// ---------------------------------------------------------------------------
__global__ __launch_bounds__(128) void table_kernel(float* __restrict__ gtab) {
    int i = blockIdx.x * 128 + threadIdx.x;
    if (i < TAB_N) gtab[i] = scale_fn(fmaf((float)i, 0.015625f, -8.0f));
}

// ---------------------------------------------------------------------------
// Kernel 1: per-chunk sums of f0 in double. grid = BATCH*NCHUNK blocks x 128.
// ---------------------------------------------------------------------------
__global__ __launch_bounds__(128) void chunk_sum_kernel(
        const float* __restrict__ f0, double* __restrict__ csum) {
    int bx = blockIdx.x;
    int t  = threadIdx.x;
    double v = (double)f0[(long)bx * CHUNK + t];
    for (int off = 32; off > 0; off >>= 1) v += __shfl_down(v, off, 64);
    __shared__ double ws[2];
    if ((t & 63) == 0) ws[t >> 6] = v;
    __syncthreads();
    if (t == 0) csum[bx] = ws[0] + ws[1];
}

// ---------------------------------------------------------------------------
// Kernel 2: per-row EXCLUSIVE scan of the NCHUNK chunk sums (in place).
// ---------------------------------------------------------------------------
__global__ __launch_bounds__(512) void chunk_scan_kernel(double* __restrict__ csum) {
    int r = blockIdx.x;
    int t = threadIdx.x;
    int lane = t & 63, w = t >> 6;
    double orig = (t < NCHUNK) ? csum[(long)r * NCHUNK + t] : 0.0;
    double v = orig;
    for (int off = 1; off < 64; off <<= 1) {
        double n = __shfl_up(v, off, 64);
        if (lane >= off) v += n;
    }
    __shared__ double wsum[8];
    if (lane == 63) wsum[w] = v;
    __syncthreads();
    double add = 0.0;
    for (int i = 0; i < w; ++i) add += wsum[i];
    v += add;
    if (t < NCHUNK) csum[(long)r * NCHUNK + t] = v - orig;   // exclusive prefix
}

// ---------------------------------------------------------------------------
// Kernel 3: main oscillator. One block = 128 consecutive samples of one row.
// - full 128x65 amp slab staged to LDS in one contiguous float4 pass
// - scale_fn via LDS table + linear interp (no transcendentals in loop)
// - sin(h*theta) via rotation recurrence (no v_sin in loop)
// - anti-alias cutoff kmax computed once per sample, bit-exact vs f0*h<22050
// ---------------------------------------------------------------------------
__global__ __launch_bounds__(128) void osc_kernel(
        const float* __restrict__ f0,
        const float* __restrict__ ha,
        const float* __restrict__ phase,
        const double* __restrict__ csum,
        const float* __restrict__ gtab,
        float* __restrict__ out) {
    int bx = blockIdx.x;
    int r  = bx / NCHUNK;
    int t  = threadIdx.x;
    int lane = t & 63, w = t >> 6;

    long sbase = (long)bx * CHUNK;
    const float* hablk = ha + sbase * 65;

    __shared__ float amp[CHUNK * 65];    // 33,280 B
    __shared__ float tab[TAB_N];         //  4,608 B

    // ---- stage table (288 float4) ----
    {
        const float4* ts = (const float4*)gtab;
        float4* td = (float4*)tab;
        td[t]       = ts[t];
        td[t + 128] = ts[t + 128];
        if (t < 32) td[t + 256] = ts[t + 256];
    }
    // ---- stage amp slab: 128*65 = 2080 float4, contiguous coalesced ----
    {
        const float4* src = (const float4*)hablk;
        float4* dst = (float4*)amp;
        #pragma unroll
        for (int i = 0; i < 16; ++i)
            dst[i * 128 + t] = src[i * 128 + t];
        if (t < 32)
            dst[16 * 128 + t] = src[16 * 128 + t];
    }

    float f0v = f0[sbase + t];

    // ---- inclusive scan of f0 in double -> nu (revolutions, mod 1) ----
    double v = (double)f0v;
    for (int off = 1; off < 64; off <<= 1) {
        double n = __shfl_up(v, off, 64);
        if (lane >= off) v += n;
    }
    __shared__ double wsum[2];
    if (lane == 63) wsum[w] = v;
    __syncthreads();                     // covers staging + wsum
    if (w == 1) v += wsum[0];
    v += csum[bx];
    double x = v * (1.0 / 44100.0) + (double)phase[r] * 0.15915494309189535;
    x -= floor(x);
    float nu = (float)x;                 // [0,1)

    // ---- exact anti-alias cutoff: max h with f0*h < 22050 (f32 semantics) ----
    float k0 = floorf(22050.0f / f0v);
    if (f0v * (k0 + 1.0f) < 22050.0f)      k0 += 1.0f;
    else if (!(f0v * k0 < 22050.0f))       k0 -= 1.0f;

    // ---- rotation recurrence init ----
    float th = 6.283185307179586f * nu;
    float s1 = __sinf(th);
    float c1 = __cosf(th);
    float s = s1, c = c1;                // sin/cos of 1*theta

    float S1 = 0.0f, S2 = 0.0f;
    #pragma unroll 8
    for (int h = 0; h < 64; ++h) {
        float a  = amp[t * 65 + 1 + h];
        float tc = fmaf(a, 64.0f, 512.0f);          // index in table space
        tc = fminf(fmaxf(tc, 0.0f), 1022.99f);
        float fi = floorf(tc);
        int   i  = (int)fi;
        float fr = tc - fi;
        float w0 = tab[i];
        float w1 = tab[i + 1];
        float wv = fmaf(fr, w1 - w0, w0);           // scale_fn(a) via interp
        wv = ((float)(h + 1) <= k0) ? wv : 0.0f;    // anti-alias mask
        S1 += wv;
        S2 = fmaf(wv, s, S2);                       // wv * sin((h+1)*theta)
        float ns = fmaf(s, c1,  c * s1);            // rotate by theta
        float nc = fmaf(c, c1, -(s * s1));
        s = ns; c = nc;
    }

    float total = scale_fn(amp[t * 65]);            // exact, once per sample
    out[sbase + t] = total * S2 / (S1 + 1e-5f);
}

// ---------------------------------------------------------------------------
extern "C" void kernel_launch(void* const* d_in, const int* in_sizes, int n_in,
                              void* d_out, int out_size, void* d_ws, size_t ws_size,
                              hipStream_t stream) {
    const float* f0    = (const float*)d_in[0];   // (32, 64000)
    const float* ha    = (const float*)d_in[1];   // (32, 64000, 65)
    const float* phase = (const float*)d_in[2];   // (32,)
    float* out = (float*)d_out;                   // (32, 64000)

    double* csum = (double*)d_ws;                            // 16000 doubles = 128 KB
    float*  gtab = (float*)((char*)d_ws + 131072);           // table after csum

    table_kernel<<<(TAB_N + 127) / 128, 128, 0, stream>>>(gtab);
    chunk_sum_kernel<<<BATCH * NCHUNK, CHUNK, 0, stream>>>(f0, csum);
    chunk_scan_kernel<<<BATCH, 512, 0, stream>>>(csum);
    osc_kernel<<<BATCH * NCHUNK, CHUNK, 0, stream>>>(f0, ha, phase, csum, gtab, out);
}